// Round 5
// baseline (217.797 us; speedup 1.0000x reference)
//
#include <hip/hip_runtime.h>

#define NUM_REGIONS 32
#define NBINS 33                        // regions 0..32 (0 dropped in the loss)
#define BATCH 4
#define DHW (160*192*192)               // 5,898,240 per volume, divisible by 4
#define NVEC_PER_BATCH (DHW/4)          // 1,474,560 float4 vectors per batch
#define BLOCKS_PER_BATCH 512
#define NBLOCKS (BATCH*BLOCKS_PER_BATCH)                 // 2048 = 8 per CU (full residency)
#define VEC_PER_BLOCK (NVEC_PER_BATCH/BLOCKS_PER_BATCH)  // 2880
#define ITERS 12                        // 11 full (256 thr) + 1 partial (64 thr)
#define COL_STRIDE 129                  // 129 % 32 == 1 -> bank = (bin+col)%32
#define QSCALE 262144.0f                // 2^18 fixed-point scale for sigmoid
#define INV_QSCALE (1.0f/262144.0f)
#define CNT_SHIFT 25
#define XS_MASK ((1u<<CNT_SHIFT)-1u)
#define EPS 1e-8f

// ---------------------------------------------------------------------------
// Kernel 1: per-thread-pair privatized LDS histogram, INTEGER ds_add_u32.
// R5 experiment: 8 blocks/CU (100% nominal occupancy) + 3-deep prefetch to
// discriminate latency-stall-bound (fix -> ~55us) vs atomic-throughput-bound
// (unchanged ~80us). Packed u32 per element:
//   bits 0..24 : round(sigmoid * 2^18) sums  (max ~96 elems/col * 2^18 < 2^25)
//   bits 25..31: element count               (max 96 per (bin,col) < 128)
// ws layout: ws[0..132) = xs sums (float), ws[132..264) = counts (float).
// ---------------------------------------------------------------------------
__global__ __launch_bounds__(256) void region_sums_kernel(
    const float* __restrict__ x,
    const int*   __restrict__ seg,
    float*       __restrict__ ws)
{
    __shared__ unsigned int hist[NBINS * COL_STRIDE];   // 17,028 B
    __shared__ float part_xs [8][NBINS];                //  1,056 B
    __shared__ float part_cnt[8][NBINS];                //  1,056 B

    const int tid = threadIdx.x;
    const int col = tid >> 1;

    for (int i = tid; i < NBINS * COL_STRIDE; i += 256) hist[i] = 0u;
    __syncthreads();

    const int batch = blockIdx.x >> 9;                  // 512 blocks per batch
    const int local = blockIdx.x & 511;
    const int vbase = batch * NVEC_PER_BATCH + local * VEC_PER_BLOCK;

    const float4* __restrict__ xv4 = (const float4*)x;
    const int4*   __restrict__ sv4 = (const int4*)seg;

    // offsets clamped inside the block's range so prefetch never goes OOB
    #define OFFK(k) ((((k)*256 + tid) < VEC_PER_BLOCK) ? ((k)*256 + tid) : (VEC_PER_BLOCK-1))

    // 3-deep rolling prefetch, named registers only
    float4 xA = xv4[vbase + OFFK(0)]; int4 sA = sv4[vbase + OFFK(0)];
    float4 xB = xv4[vbase + OFFK(1)]; int4 sB = sv4[vbase + OFFK(1)];
    float4 xC = xv4[vbase + OFFK(2)]; int4 sC = sv4[vbase + OFFK(2)];

    #pragma unroll 1
    for (int k = 0; k < ITERS; ++k) {
        const int kn = (k + 3 < ITERS) ? (k + 3) : (ITERS - 1);
        float4 xN = xv4[vbase + OFFK(kn)];
        int4   sN = sv4[vbase + OFFK(kn)];

        float p0 = __fdividef(1.0f, 1.0f + __expf(-xA.x));
        float p1 = __fdividef(1.0f, 1.0f + __expf(-xA.y));
        float p2 = __fdividef(1.0f, 1.0f + __expf(-xA.z));
        float p3 = __fdividef(1.0f, 1.0f + __expf(-xA.w));

        unsigned q0 = (unsigned)(fmaf(p0, QSCALE, 0.5f)) + (1u << CNT_SHIFT);
        unsigned q1 = (unsigned)(fmaf(p1, QSCALE, 0.5f)) + (1u << CNT_SHIFT);
        unsigned q2 = (unsigned)(fmaf(p2, QSCALE, 0.5f)) + (1u << CNT_SHIFT);
        unsigned q3 = (unsigned)(fmaf(p3, QSCALE, 0.5f)) + (1u << CNT_SHIFT);

        // guard only the commit: all iters full except k==11 (tid<64)
        if (k * 256 + tid < VEC_PER_BLOCK) {
            atomicAdd(&hist[sA.x * COL_STRIDE + col], q0);
            atomicAdd(&hist[sA.y * COL_STRIDE + col], q1);
            atomicAdd(&hist[sA.z * COL_STRIDE + col], q2);
            atomicAdd(&hist[sA.w * COL_STRIDE + col], q3);
        }

        xA = xB; sA = sB; xB = xC; sB = sC; xC = xN; sC = sN;
    }
    #undef OFFK
    __syncthreads();

    // Parallel reduce: 8 groups x 32 bins (bin 0 dropped); group g sums 16
    // of the 128 columns. Banks (bin + g*16 + j) % 32 -> conflict-free.
    {
        const int bin = (tid & 31) + 1;
        const int g   = tid >> 5;
        float xs = 0.0f, cnt = 0.0f;
        #pragma unroll
        for (int j = 0; j < 16; ++j) {
            unsigned V = hist[bin * COL_STRIDE + g * 16 + j];
            cnt += (float)(V >> CNT_SHIFT);
            xs  += (float)(V & XS_MASK);
        }
        part_xs [g][bin] = xs;
        part_cnt[g][bin] = cnt;
    }
    __syncthreads();

    if (tid < 32) {
        const int bin = tid + 1;
        float xs = 0.0f, cnt = 0.0f;
        #pragma unroll
        for (int g = 0; g < 8; ++g) {
            xs  += part_xs [g][bin];
            cnt += part_cnt[g][bin];
        }
        atomicAdd(&ws[batch * NBINS + bin], xs * INV_QSCALE);
        atomicAdd(&ws[BATCH * NBINS + batch * NBINS + bin], cnt);
    }
}

// ---------------------------------------------------------------------------
// Kernel 2: dice + mean epilogue. One wave; lane r handles region r (1..32).
// ---------------------------------------------------------------------------
__global__ void region_dice_final_kernel(
    const float* __restrict__ ws,
    float*       __restrict__ out)
{
    const int lane = threadIdx.x;   // 0..63
    float loss_sum = 0.0f;

    for (int b = 0; b < BATCH; ++b) {
        bool  valid = false;
        float dice  = 0.0f;
        if (lane >= 1 && lane <= NUM_REGIONS) {
            float xs  = ws[b * NBINS + lane];
            float cnt = ws[BATCH * NBINS + b * NBINS + lane];
            valid = (cnt > 0.0f);
            if (valid) dice = 2.0f * xs / (xs + cnt + EPS);
        }
        unsigned long long m = __ballot(valid);
        int n_valid = __popcll(m);

        float s = dice;
        #pragma unroll
        for (int off = 32; off >= 1; off >>= 1) s += __shfl_down(s, off);

        float mean_dice = s / (float)((n_valid > 1) ? n_valid : 1);
        float loss_b    = (n_valid > 0) ? (1.0f - mean_dice) : 1.0f;
        loss_sum += loss_b;
    }

    if (lane == 0) out[0] = loss_sum * (1.0f / BATCH);
}

extern "C" void kernel_launch(void* const* d_in, const int* in_sizes, int n_in,
                              void* d_out, int out_size, void* d_ws, size_t ws_size,
                              hipStream_t stream)
{
    const float* x   = (const float*)d_in[0];
    const int*   seg = (const int*)d_in[1];
    float*       ws  = (float*)d_ws;

    // d_ws is poisoned with 0xAA before every timed launch — zero the bins.
    hipMemsetAsync(d_ws, 0, 2 * BATCH * NBINS * sizeof(float), stream);

    region_sums_kernel<<<NBLOCKS, 256, 0, stream>>>(x, seg, ws);
    region_dice_final_kernel<<<1, 64, 0, stream>>>(ws, (float*)d_out);
}